// Round 7
// baseline (165.341 us; speedup 1.0000x reference)
//
#include <hip/hip_runtime.h>
#include <math.h>

#define BATCH 16
#define NUM_HEADS 16
#define HEAD_DIM 64
#define HIDDEN 1024
#define BLOCK_SIZE 16
#define MAX_CTX 4096
#define BLOCKS_PER_SEQ 256
#define SPLITS 8
#define CHUNKS 4
#define CHUNK_F4 64    // (HIDDEN/CHUNKS)/4

// workspace layout in floats (R3 layout)
#define Q_OFF   0                  // 16384 floats (q pre-scaled by 0.125*log2e)
#define K_OFF   16384
#define V_OFF   32768
#define AO_OFF  49152
#define PML_OFF 65536              // BATCH*NUM_HEADS*SPLITS*2 = 4096
#define PO_OFF  69632              // BATCH*NUM_HEADS*SPLITS*64 = 131072
#define PART_OFF 200704            // CHUNKS*3072*16 = 196608

#define LOG2E 1.4426950408889634f

// DIAGNOSTIC BUILD: attn_partial runs NPASSES full scans (identical work,
// state reset per pass, last pass's result is the real one). Purpose: push
// the dispatch above the harness's 1GB fills (~160us) so its rocprof row
// (FETCH_SIZE / hbm_gbps / VALUBusy / Occupancy) lands in the top-5 table.
#define NPASSES 3

// Split-K GEMV partial: rows 0..1023 -> W0, 1024..2047 -> W1, 2048..3071 -> W2.
__global__ void proj_partial(const float* __restrict__ X,
                             const float* __restrict__ W0,
                             const float* __restrict__ W1,
                             const float* __restrict__ W2,
                             float* __restrict__ part, int NR) {
    const int tid = threadIdx.x;
    const int b = tid & 15;
    const int r = tid >> 4;                  // 0..15
    const int row = blockIdx.x * 16 + r;
    const int c = blockIdx.y;
    const int m = row >> 10;
    const int row_in = row & 1023;
    const float* W = (m == 0) ? W0 : (m == 1) ? W1 : W2;

    const float4* wrow = (const float4*)(W + (size_t)row_in * HIDDEN) + c * CHUNK_F4;
    const float4* xrow = (const float4*)(X + (size_t)b * HIDDEN) + c * CHUNK_F4;
    float acc = 0.f;
#pragma unroll 16
    for (int i = 0; i < CHUNK_F4; ++i) {
        float4 w4 = wrow[i];
        float4 x4 = xrow[i];
        acc += w4.x * x4.x + w4.y * x4.y + w4.z * x4.z + w4.w * x4.w;
    }
    part[((size_t)c * NR + row) * 16 + b] = acc;
}

// Combine q/k/v partials; q gets pre-scaled by 0.125*log2e.
__global__ void qkv_combine(const float* __restrict__ part,
                            float* __restrict__ q_ws,
                            float* __restrict__ k_ws,
                            float* __restrict__ v_ws) {
    const int idx = blockIdx.x * 256 + threadIdx.x;  // row*16 + b, rows 0..3071
    const int row = idx >> 4;
    const int b = idx & 15;
    float s = 0.f;
#pragma unroll
    for (int c = 0; c < CHUNKS; ++c) s += part[((size_t)c * 3072 + row) * 16 + b];
    const int m = row >> 10;
    const int r = row & 1023;
    if (m == 0)      q_ws[b * HIDDEN + r] = s * (0.125f * LOG2E);
    else if (m == 1) k_ws[b * HIDDEN + r] = s;
    else             v_ws[b * HIDDEN + r] = s;
}

// Final combine for the output projection (rows 0..1023).
__global__ void out_combine(const float* __restrict__ part,
                            float* __restrict__ out) {
    const int idx = blockIdx.x * 256 + threadIdx.x;  // row*16 + b
    const int row = idx >> 4;
    const int b = idx & 15;
    float s = 0.f;
#pragma unroll
    for (int c = 0; c < CHUNKS; ++c) s += part[((size_t)c * 1024 + row) * 16 + b];
    out[(size_t)b * HIDDEN + row] = s;
}

// issue 8 x 16B loads for 64-token iteration IT (this wave's 16-token page)
#define LOAD_KV(IT, K0, K1, K2, K3, V0, V1, V2, V3)                              \
    do {                                                                          \
        const int blk_ = bt_lds[(IT) * 4 + w];                                    \
        const size_t base_ = ((size_t)blk_ * BLOCK_SIZE + g) * 1024 + hoff;       \
        const float* kp_ = key_cache + base_;                                     \
        const float* vp_ = value_cache + base_;                                   \
        K0 = *(const float4*)(kp_);                                               \
        K1 = *(const float4*)(kp_ + 4096);                                        \
        K2 = *(const float4*)(kp_ + 8192);                                        \
        K3 = *(const float4*)(kp_ + 12288);                                       \
        V0 = *(const float4*)(vp_);                                               \
        V1 = *(const float4*)(vp_ + 4096);                                        \
        V2 = *(const float4*)(vp_ + 8192);                                        \
        V3 = *(const float4*)(vp_ + 12288);                                       \
    } while (0)

#define COMPUTE(IT, K0, K1, K2, K3, V0, V1, V2, V3)                               \
    do {                                                                          \
        float d0_ = K0.x * q4.x + K0.y * q4.y + K0.z * q4.z + K0.w * q4.w;        \
        float d1_ = K1.x * q4.x + K1.y * q4.y + K1.z * q4.z + K1.w * q4.w;        \
        float d2_ = K2.x * q4.x + K2.y * q4.y + K2.z * q4.z + K2.w * q4.w;        \
        float d3_ = K3.x * q4.x + K3.y * q4.y + K3.z * q4.z + K3.w * q4.w;        \
        d0_ += __shfl_xor(d0_, 1); d1_ += __shfl_xor(d1_, 1);                     \
        d2_ += __shfl_xor(d2_, 1); d3_ += __shfl_xor(d3_, 1);                     \
        d0_ += __shfl_xor(d0_, 2); d1_ += __shfl_xor(d1_, 2);                     \
        d2_ += __shfl_xor(d2_, 2); d3_ += __shfl_xor(d3_, 2);                     \
        d0_ += __shfl_xor(d0_, 4); d1_ += __shfl_xor(d1_, 4);                     \
        d2_ += __shfl_xor(d2_, 4); d3_ += __shfl_xor(d3_, 4);                     \
        d0_ += __shfl_xor(d0_, 8); d1_ += __shfl_xor(d1_, 8);                     \
        d2_ += __shfl_xor(d2_, 8); d3_ += __shfl_xor(d3_, 8);                     \
        const int tb_ = t0 + (IT) * 64 + w * 16 + g;                              \
        if (tb_ + 0  >= t1) d0_ = -INFINITY;                                      \
        if (tb_ + 4  >= t1) d1_ = -INFINITY;                                      \
        if (tb_ + 8  >= t1) d2_ = -INFINITY;                                      \
        if (tb_ + 12 >= t1) d3_ = -INFINITY;                                      \
        const float mx_ = fmaxf(fmaxf(d0_, d1_), fmaxf(d2_, d3_));                \
        const float m_new_ = fmaxf(m, mx_);                                       \
        const float corr_ = exp2f(m - m_new_);                                    \
        const float p0_ = exp2f(d0_ - m_new_);                                    \
        const float p1_ = exp2f(d1_ - m_new_);                                    \
        const float p2_ = exp2f(d2_ - m_new_);                                    \
        const float p3_ = exp2f(d3_ - m_new_);                                    \
        l = l * corr_ + ((p0_ + p1_) + (p2_ + p3_));                              \
        o4.x = o4.x * corr_ + p0_ * V0.x + p1_ * V1.x + p2_ * V2.x + p3_ * V3.x;  \
        o4.y = o4.y * corr_ + p0_ * V0.y + p1_ * V1.y + p2_ * V2.y + p3_ * V3.y;  \
        o4.z = o4.z * corr_ + p0_ * V0.z + p1_ * V1.z + p2_ * V2.z + p3_ * V3.z;  \
        o4.w = o4.w * corr_ + p0_ * V0.w + p1_ * V1.w + p2_ * V2.w + p3_ * V3.w;  \
        m = m_new_;                                                               \
    } while (0)

// Flash-decode partial: grid (SPLITS, NUM_HEADS, BATCH), 256 threads.
// DIAGNOSTIC: NPASSES identical scans; only the last pass's state is stored.
__global__ __launch_bounds__(256, 4) void attn_partial(
                             const float* __restrict__ q_ws,
                             const float* __restrict__ key_cache,
                             const float* __restrict__ value_cache,
                             const int* __restrict__ block_table,
                             const int* __restrict__ positions,
                             float* __restrict__ part_ml,
                             float* __restrict__ part_o) {
    const int s = blockIdx.x;
    const int h = blockIdx.y;
    const int b = blockIdx.z;
    const int tid = threadIdx.x;          // 0..255
    const int lane = tid & 63;
    const int w = tid >> 6;               // wave 0..3
    const int g = lane >> 4;              // group-in-wave 0..3
    const int sub = lane & 15;            // 0..15
    const int gid = w * 4 + g;            // 0..15

    __shared__ int bt_lds[32];
    __shared__ float gm[16];
    __shared__ float gl[16];
    __shared__ float go[16][64];

    const int pos = positions[b];
    const int chunk = ((pos + SPLITS * 64 - 1) / (SPLITS * 64)) * 64;  // mult of 64
    const int t0 = s * chunk;
    const int t1 = min(t0 + chunk, pos);
    const int nvalid = t1 - t0;
    const int niter = (nvalid + 63) >> 6;

    // q load (pre-scaled) is independent of LDS -- issue before the barrier
    float4 q4 = ((const float4*)(q_ws + (size_t)b * HIDDEN + h * HEAD_DIM))[sub];

    // stage 32 entries; t0>>4 <= 224 so index <= 255: always in-bounds.
    if (tid < 32) {
        bt_lds[tid] = block_table[b * BLOCKS_PER_SEQ + (t0 >> 4) + tid];
    }
    __syncthreads();

    const int hoff = h * HEAD_DIM + sub * 4;

    float m, l;
    float4 o4;
    float4 kA0, kA1, kA2, kA3, vA0, vA1, vA2, vA3;
    float4 kB0, kB1, kB2, kB3, vB0, vB1, vB2, vB3;

    for (int p = 0; p < NPASSES; ++p) {
        m = -1e30f;
        l = 0.f;
        o4.x = 0.f; o4.y = 0.f; o4.z = 0.f; o4.w = 0.f;

        if (niter > 0) {
            LOAD_KV(0, kA0, kA1, kA2, kA3, vA0, vA1, vA2, vA3);
            int it = 0;
            while (true) {
                if (it + 1 < niter) LOAD_KV(it + 1, kB0, kB1, kB2, kB3, vB0, vB1, vB2, vB3);
                COMPUTE(it, kA0, kA1, kA2, kA3, vA0, vA1, vA2, vA3);
                ++it;
                if (it >= niter) break;
                if (it + 1 < niter) LOAD_KV(it + 1, kA0, kA1, kA2, kA3, vA0, vA1, vA2, vA3);
                COMPUTE(it, kB0, kB1, kB2, kB3, vB0, vB1, vB2, vB3);
                ++it;
                if (it >= niter) break;
            }
        }
        // keep pass results live so earlier passes aren't dead-code-eliminated
        asm volatile("" : "+v"(m), "+v"(l), "+v"(o4.x), "+v"(o4.y), "+v"(o4.z), "+v"(o4.w));
    }

    go[gid][sub * 4 + 0] = o4.x;
    go[gid][sub * 4 + 1] = o4.y;
    go[gid][sub * 4 + 2] = o4.z;
    go[gid][sub * 4 + 3] = o4.w;
    if (sub == 0) { gm[gid] = m; gl[gid] = l; }
    __syncthreads();

    if (tid < 64) {
        const int d = tid;
        float M = -1e30f;
#pragma unroll
        for (int gi = 0; gi < 16; ++gi) M = fmaxf(M, gm[gi]);
        float L = 0.f, O = 0.f;
#pragma unroll
        for (int gi = 0; gi < 16; ++gi) {
            const float sc = exp2f(gm[gi] - M);   // log2-domain maxes
            L += gl[gi] * sc;
            O += go[gi][d] * sc;
        }
        const int pidx = (b * NUM_HEADS + h) * SPLITS + s;
        part_o[(size_t)pidx * 64 + d] = O;
        if (d == 0) {
            part_ml[pidx * 2 + 0] = M;   // log2 domain
            part_ml[pidx * 2 + 1] = L;
        }
    }
}

// Merge split partials + the new-token (tok == pos) term. grid = B*H, 64 thr.
__global__ void attn_reduce(const float* __restrict__ q_ws,
                            const float* __restrict__ k_ws,
                            const float* __restrict__ v_ws,
                            const float* __restrict__ part_ml,
                            const float* __restrict__ part_o,
                            float* __restrict__ attn_out) {
    const int bh = blockIdx.x;          // b*16 + h
    const int b = bh >> 4;
    const int h = bh & 15;
    const int d = threadIdx.x;          // 0..63

    const size_t vecoff = (size_t)b * HIDDEN + h * HEAD_DIM + d;
    const float qd = q_ws[vecoff];      // pre-scaled -> dot is log2-domain
    const float kd = k_ws[vecoff];
    float pr = qd * kd;
    pr += __shfl_xor(pr, 1);
    pr += __shfl_xor(pr, 2);
    pr += __shfl_xor(pr, 4);
    pr += __shfl_xor(pr, 8);
    pr += __shfl_xor(pr, 16);
    pr += __shfl_xor(pr, 32);
    const float s_new = pr;

    float2 ml0 = ((const float2*)part_ml)[bh * SPLITS + 0];
    float2 ml1 = ((const float2*)part_ml)[bh * SPLITS + 1];
    float2 ml2 = ((const float2*)part_ml)[bh * SPLITS + 2];
    float2 ml3 = ((const float2*)part_ml)[bh * SPLITS + 3];
    float2 ml4 = ((const float2*)part_ml)[bh * SPLITS + 4];
    float2 ml5 = ((const float2*)part_ml)[bh * SPLITS + 5];
    float2 ml6 = ((const float2*)part_ml)[bh * SPLITS + 6];
    float2 ml7 = ((const float2*)part_ml)[bh * SPLITS + 7];

    float M = s_new;
    M = fmaxf(M, fmaxf(fmaxf(ml0.x, ml1.x), fmaxf(ml2.x, ml3.x)));
    M = fmaxf(M, fmaxf(fmaxf(ml4.x, ml5.x), fmaxf(ml6.x, ml7.x)));

    const float sc0 = exp2f(ml0.x - M), sc1 = exp2f(ml1.x - M);
    const float sc2 = exp2f(ml2.x - M), sc3 = exp2f(ml3.x - M);
    const float sc4 = exp2f(ml4.x - M), sc5 = exp2f(ml5.x - M);
    const float sc6 = exp2f(ml6.x - M), sc7 = exp2f(ml7.x - M);

    float L = exp2f(s_new - M)
            + ml0.y * sc0 + ml1.y * sc1 + ml2.y * sc2 + ml3.y * sc3
            + ml4.y * sc4 + ml5.y * sc5 + ml6.y * sc6 + ml7.y * sc7;
    float O = exp2f(s_new - M) * v_ws[vecoff];
    const float* po = part_o + (size_t)bh * SPLITS * 64 + d;
    O += po[0 * 64] * sc0 + po[1 * 64] * sc1 + po[2 * 64] * sc2 + po[3 * 64] * sc3
       + po[4 * 64] * sc4 + po[5 * 64] * sc5 + po[6 * 64] * sc6 + po[7 * 64] * sc7;

    attn_out[vecoff] = O / L;
}

extern "C" void kernel_launch(void* const* d_in, const int* in_sizes, int n_in,
                              void* d_out, int out_size, void* d_ws, size_t ws_size,
                              hipStream_t stream) {
    const float* hidden      = (const float*)d_in[0];
    const float* key_cache   = (const float*)d_in[1];
    const float* value_cache = (const float*)d_in[2];
    const int*   block_table = (const int*)d_in[3];
    const int*   positions   = (const int*)d_in[4];
    const float* Wq          = (const float*)d_in[5];
    const float* Wk          = (const float*)d_in[6];
    const float* Wv          = (const float*)d_in[7];
    const float* Wo          = (const float*)d_in[8];
    float* out = (float*)d_out;

    float* ws = (float*)d_ws;
    float* q_ws  = ws + Q_OFF;
    float* k_ws  = ws + K_OFF;
    float* v_ws  = ws + V_OFF;
    float* ao_ws = ws + AO_OFF;
    float* pml   = ws + PML_OFF;
    float* po    = ws + PO_OFF;
    float* part  = ws + PART_OFF;

    // 1) q/k/v projections: 3072 rows x 4 column-chunks
    proj_partial<<<dim3(192, CHUNKS), 256, 0, stream>>>(hidden, Wq, Wk, Wv, part, 3072);
    qkv_combine<<<192, 256, 0, stream>>>(part, q_ws, k_ws, v_ws);

    // 2) flash-decode partials (DIAGNOSTIC: 3 passes inside the kernel)
    attn_partial<<<dim3(SPLITS, NUM_HEADS, BATCH), 256, 0, stream>>>(
        q_ws, key_cache, value_cache, block_table, positions, pml, po);

    // 3) merge splits + new-token contribution
    attn_reduce<<<BATCH * NUM_HEADS, 64, 0, stream>>>(q_ws, k_ws, v_ws, pml, po, ao_ws);

    // 4) output projection: 1024 rows x 4 column-chunks
    proj_partial<<<dim3(64, CHUNKS), 256, 0, stream>>>(ao_ws, Wo, Wo, Wo, part, 1024);
    out_combine<<<64, 256, 0, stream>>>(part, out);
}

// Round 8
// 105.639 us; speedup vs baseline: 1.5652x; 1.5652x over previous
//
#include <hip/hip_runtime.h>
#include <math.h>

#define BATCH 16
#define NUM_HEADS 16
#define HEAD_DIM 64
#define HIDDEN 1024
#define BLOCK_SIZE 16
#define MAX_CTX 4096
#define BLOCKS_PER_SEQ 256
#define CHUNKS 4
#define CHUNK_F4 64    // (HIDDEN/CHUNKS)/4

#define NBLOCKS_ATTN 512
#define NWAVES_ATTN (NBLOCKS_ATTN * 4)      // 2048
#define MAX_ITEMS 4096                      // 16 * 256

// workspace layout in floats
#define Q_OFF     0            // 16384 (q pre-scaled by 0.125*log2e)
#define K_OFF     16384
#define V_OFF     32768
#define AO_OFF    49152
#define PART_OFF  65536        // 196608 (proj partials)
#define ITEMS_OFF 262144       // 4096 ints
#define CUM_OFF   266240       // 17 ints
#define CNT_OFF   266260       // 1 uint
#define PML_OFF   270336       // MAX_ITEMS*32 = 131072
#define PO_OFF    401408       // MAX_ITEMS*1024 = 4194304
#define ML2_OFF   4595712      // 16*16*16*2 = 8192
#define O2_OFF    4603904      // 16*16*16*64 = 262144
// end 4866048 floats ~= 19.5 MB

#define LOG2E 1.4426950408889634f

// Split-K GEMV partial: rows 0..1023 -> W0, 1024..2047 -> W1, 2048..3071 -> W2.
__global__ void proj_partial(const float* __restrict__ X,
                             const float* __restrict__ W0,
                             const float* __restrict__ W1,
                             const float* __restrict__ W2,
                             float* __restrict__ part, int NR) {
    const int tid = threadIdx.x;
    const int b = tid & 15;
    const int r = tid >> 4;                  // 0..15
    const int row = blockIdx.x * 16 + r;
    const int c = blockIdx.y;
    const int m = row >> 10;
    const int row_in = row & 1023;
    const float* W = (m == 0) ? W0 : (m == 1) ? W1 : W2;

    const float4* wrow = (const float4*)(W + (size_t)row_in * HIDDEN) + c * CHUNK_F4;
    const float4* xrow = (const float4*)(X + (size_t)b * HIDDEN) + c * CHUNK_F4;
    float acc = 0.f;
#pragma unroll 16
    for (int i = 0; i < CHUNK_F4; ++i) {
        float4 w4 = wrow[i];
        float4 x4 = xrow[i];
        acc += w4.x * x4.x + w4.y * x4.y + w4.z * x4.z + w4.w * x4.w;
    }
    part[((size_t)c * NR + row) * 16 + b] = acc;
}

// Combine q/k/v partials (q pre-scaled). Block 0 additionally builds the
// item list (one item per valid cache block, ordered by (b, cb)), the cum
// prefix table, and resets the steal counter.
__global__ void qkv_combine(const float* __restrict__ part,
                            const int* __restrict__ positions,
                            float* __restrict__ q_ws,
                            float* __restrict__ k_ws,
                            float* __restrict__ v_ws,
                            int* __restrict__ items,
                            int* __restrict__ cum,
                            unsigned* __restrict__ counter) {
    const int idx = blockIdx.x * 256 + threadIdx.x;  // row*16 + b, rows 0..3071
    const int row = idx >> 4;
    const int b = idx & 15;
    float s = 0.f;
#pragma unroll
    for (int c = 0; c < CHUNKS; ++c) s += part[((size_t)c * 3072 + row) * 16 + b];
    const int m = row >> 10;
    const int r = row & 1023;
    if (m == 0)      q_ws[b * HIDDEN + r] = s * (0.125f * LOG2E);
    else if (m == 1) k_ws[b * HIDDEN + r] = s;
    else             v_ws[b * HIDDEN + r] = s;

    if (blockIdx.x == 0) {
        __shared__ int cum_s[17];
        if (threadIdx.x == 0) {
            int c = 0;
            cum_s[0] = 0;
            for (int bb = 0; bb < 16; ++bb) {
                c += (positions[bb] + 15) >> 4;
                cum_s[bb + 1] = c;
            }
            *counter = NWAVES_ATTN;
        }
        __syncthreads();
        const int total = cum_s[16];
        for (int i = threadIdx.x; i < total; i += 256) {
            int bb = 0;
#pragma unroll
            for (int t = 1; t < 16; ++t) if (i >= cum_s[t]) bb = t;
            items[i] = (bb << 16) | (i - cum_s[bb]);
        }
        if (threadIdx.x < 17) cum[threadIdx.x] = cum_s[threadIdx.x];
    }
}

// Final combine for the output projection (rows 0..1023).
__global__ void out_combine(const float* __restrict__ part,
                            float* __restrict__ out) {
    const int idx = blockIdx.x * 256 + threadIdx.x;  // row*16 + b
    const int row = idx >> 4;
    const int b = idx & 15;
    float s = 0.f;
#pragma unroll
    for (int c = 0; c < CHUNKS; ++c) s += part[((size_t)c * 1024 + row) * 16 + b];
    out[(size_t)b * HIDDEN + row] = s;
}

// Load one 4KB K slot row + 4KB V slot row: 4+4 contiguous 1KB wave-loads.
#define SLOT_LOAD(S, K0, K1, K2, K3, V0, V1, V2, V3)                         \
    do {                                                                      \
        const float4* kp_ = (const float4*)kbase + (S) * 256 + lane;          \
        const float4* vp_ = (const float4*)vbase + (S) * 256 + lane;          \
        K0 = kp_[0]; K1 = kp_[64]; K2 = kp_[128]; K3 = kp_[192];              \
        V0 = vp_[0]; V1 = vp_[64]; V2 = vp_[128]; V3 = vp_[192];              \
    } while (0)

// One token (slot S): 4 head-dots (fragment i -> head 4i+g), 16-lane reduce,
// online-softmax update of 4 per-lane head states. Wave-uniform validity.
#define SLOT_COMP(S, K0, K1, K2, K3, V0, V1, V2, V3)                          \
    do {                                                                      \
        const int t_ = tokbase + (S);                                         \
        if (t_ < pos) {                                                       \
            float d0_ = K0.x*q0.x + K0.y*q0.y + K0.z*q0.z + K0.w*q0.w;        \
            float d1_ = K1.x*q1.x + K1.y*q1.y + K1.z*q1.z + K1.w*q1.w;        \
            float d2_ = K2.x*q2.x + K2.y*q2.y + K2.z*q2.z + K2.w*q2.w;        \
            float d3_ = K3.x*q3.x + K3.y*q3.y + K3.z*q3.z + K3.w*q3.w;        \
            d0_ += __shfl_xor(d0_, 1); d1_ += __shfl_xor(d1_, 1);             \
            d2_ += __shfl_xor(d2_, 1); d3_ += __shfl_xor(d3_, 1);             \
            d0_ += __shfl_xor(d0_, 2); d1_ += __shfl_xor(d1_, 2);             \
            d2_ += __shfl_xor(d2_, 2); d3_ += __shfl_xor(d3_, 2);             \
            d0_ += __shfl_xor(d0_, 4); d1_ += __shfl_xor(d1_, 4);             \
            d2_ += __shfl_xor(d2_, 4); d3_ += __shfl_xor(d3_, 4);             \
            d0_ += __shfl_xor(d0_, 8); d1_ += __shfl_xor(d1_, 8);             \
            d2_ += __shfl_xor(d2_, 8); d3_ += __shfl_xor(d3_, 8);             \
            float mn_, c_, p_;                                                \
            mn_ = fmaxf(m0, d0_); c_ = exp2f(m0 - mn_); p_ = exp2f(d0_ - mn_);\
            l0 = l0 * c_ + p_;                                                \
            o0.x = o0.x*c_ + p_*V0.x; o0.y = o0.y*c_ + p_*V0.y;               \
            o0.z = o0.z*c_ + p_*V0.z; o0.w = o0.w*c_ + p_*V0.w; m0 = mn_;     \
            mn_ = fmaxf(m1, d1_); c_ = exp2f(m1 - mn_); p_ = exp2f(d1_ - mn_);\
            l1 = l1 * c_ + p_;                                                \
            o1.x = o1.x*c_ + p_*V1.x; o1.y = o1.y*c_ + p_*V1.y;               \
            o1.z = o1.z*c_ + p_*V1.z; o1.w = o1.w*c_ + p_*V1.w; m1 = mn_;     \
            mn_ = fmaxf(m2, d2_); c_ = exp2f(m2 - mn_); p_ = exp2f(d2_ - mn_);\
            l2 = l2 * c_ + p_;                                                \
            o2.x = o2.x*c_ + p_*V2.x; o2.y = o2.y*c_ + p_*V2.y;               \
            o2.z = o2.z*c_ + p_*V2.z; o2.w = o2.w*c_ + p_*V2.w; m2 = mn_;     \
            mn_ = fmaxf(m3, d3_); c_ = exp2f(m3 - mn_); p_ = exp2f(d3_ - mn_);\
            l3 = l3 * c_ + p_;                                                \
            o3.x = o3.x*c_ + p_*V3.x; o3.y = o3.y*c_ + p_*V3.y;               \
            o3.z = o3.z*c_ + p_*V3.z; o3.w = o3.w*c_ + p_*V3.w; m3 = mn_;     \
        }                                                                     \
    } while (0)

// Flash-decode: item = one cache block (16 tokens), ALL 16 heads, one wave.
// Each 128KB K+V region is read contiguously, exactly once, by one wave ->
// single temporal visit per DRAM row. Static-first + atomic stealing.
__global__ __launch_bounds__(256, 3) void attn_partial(
        const float* __restrict__ q_ws,
        const float* __restrict__ key_cache,
        const float* __restrict__ value_cache,
        const int* __restrict__ block_table,
        const int* __restrict__ positions,
        const int* __restrict__ items,
        const int* __restrict__ cum,
        unsigned* __restrict__ counter,
        float* __restrict__ part_ml,
        float* __restrict__ part_o) {
    const int lane = threadIdx.x & 63;
    const int g = lane >> 4;              // 0..3
    const int sub = lane & 15;
    const int gid = blockIdx.x * 4 + (threadIdx.x >> 6);
    const int total = cum[16];

    int idx = gid;                        // static first item; steal afterwards
    while (idx < total) {
        const int item = items[idx];
        const int b = item >> 16;
        const int cb = item & 0xffff;
        const int pos = positions[b];
        const int blk = block_table[b * BLOCKS_PER_SEQ + cb];
        const int tokbase = cb * 16;
        const float* kbase = key_cache + (size_t)blk * 16384;
        const float* vbase = value_cache + (size_t)blk * 16384;

        const float4* Q4 = (const float4*)q_ws + b * 256 + lane;
        const float4 q0 = Q4[0];
        const float4 q1 = Q4[64];
        const float4 q2 = Q4[128];
        const float4 q3 = Q4[192];

        float m0 = -1e30f, m1 = -1e30f, m2 = -1e30f, m3 = -1e30f;
        float l0 = 0.f, l1 = 0.f, l2 = 0.f, l3 = 0.f;
        float4 o0 = {0,0,0,0}, o1 = {0,0,0,0}, o2 = {0,0,0,0}, o3 = {0,0,0,0};

        float4 kA0, kA1, kA2, kA3, vA0, vA1, vA2, vA3;
        float4 kB0, kB1, kB2, kB3, vB0, vB1, vB2, vB3;

        SLOT_LOAD(0, kA0, kA1, kA2, kA3, vA0, vA1, vA2, vA3);
#pragma unroll
        for (int s = 0; s < 16; s += 2) {
            SLOT_LOAD(s + 1, kB0, kB1, kB2, kB3, vB0, vB1, vB2, vB3);
            SLOT_COMP(s, kA0, kA1, kA2, kA3, vA0, vA1, vA2, vA3);
            if (s + 2 < 16)
                SLOT_LOAD(s + 2, kA0, kA1, kA2, kA3, vA0, vA1, vA2, vA3);
            SLOT_COMP(s + 1, kB0, kB1, kB2, kB3, vB0, vB1, vB2, vB3);
        }

        // flush per-item partials (16 heads)
        float4* PO4 = (float4*)part_o + (size_t)idx * 256 + lane;
        PO4[0]   = o0;
        PO4[64]  = o1;
        PO4[128] = o2;
        PO4[192] = o3;
        if (sub == 0) {
            float* ml = part_ml + (size_t)idx * 32;
            ml[(0  + g) * 2 + 0] = m0; ml[(0  + g) * 2 + 1] = l0;
            ml[(4  + g) * 2 + 0] = m1; ml[(4  + g) * 2 + 1] = l1;
            ml[(8  + g) * 2 + 0] = m2; ml[(8  + g) * 2 + 1] = l2;
            ml[(12 + g) * 2 + 0] = m3; ml[(12 + g) * 2 + 1] = l3;
        }

        unsigned nx = 0;
        if (lane == 0) nx = atomicAdd(counter, 1u);
        nx = (unsigned)__shfl((int)nx, 0);
        idx = (int)nx;
    }
}

// Level-1 reduce: block (b, j) merges items {j, j+16, j+32, ...} of batch b.
// Thread (h = tid>>4, q = tid&15) merges head h, dims q*4..q*4+3.
__global__ void attn_reduce1(const int* __restrict__ positions,
                             const int* __restrict__ cum,
                             const float* __restrict__ part_ml,
                             const float* __restrict__ part_o,
                             float* __restrict__ ml2,
                             float* __restrict__ o2) {
    const int b = blockIdx.x;
    const int j = blockIdx.y;             // chunk 0..15
    const int h = threadIdx.x >> 4;
    const int q = threadIdx.x & 15;
    const int base = cum[b];
    const int nb = (positions[b] + 15) >> 4;

    float M = -1e30f, L = 0.f;
    float4 O = {0.f, 0.f, 0.f, 0.f};
    for (int i = j; i < nb; i += 16) {
        const int item = base + i;
        const float2 ml = ((const float2*)part_ml)[(size_t)item * 16 + h];
        const float4 o = ((const float4*)part_o)[(size_t)item * 256 + h * 16 + q];
        const float Mn = fmaxf(M, ml.x);
        const float ca = exp2f(M - Mn);
        const float cb = exp2f(ml.x - Mn);
        L = L * ca + ml.y * cb;
        O.x = O.x * ca + o.x * cb;
        O.y = O.y * ca + o.y * cb;
        O.z = O.z * ca + o.z * cb;
        O.w = O.w * ca + o.w * cb;
        M = Mn;
    }
    const int oi = (b * 16 + j) * 16 + h;
    ((float4*)o2)[oi * 16 + q] = O;
    if (q == 0) ((float2*)ml2)[oi] = make_float2(M, L);
}

// Level-2: merge 16 chunk-partials + the new-token term. grid = B*H, 64 thr.
__global__ void attn_reduce2(const float* __restrict__ q_ws,
                             const float* __restrict__ k_ws,
                             const float* __restrict__ v_ws,
                             const float* __restrict__ ml2,
                             const float* __restrict__ o2,
                             float* __restrict__ attn_out) {
    const int bh = blockIdx.x;          // b*16 + h
    const int b = bh >> 4;
    const int h = bh & 15;
    const int d = threadIdx.x;          // 0..63

    const size_t vecoff = (size_t)b * HIDDEN + h * HEAD_DIM + d;
    float pr = q_ws[vecoff] * k_ws[vecoff];   // q pre-scaled -> log2 domain
    pr += __shfl_xor(pr, 1);
    pr += __shfl_xor(pr, 2);
    pr += __shfl_xor(pr, 4);
    pr += __shfl_xor(pr, 8);
    pr += __shfl_xor(pr, 16);
    pr += __shfl_xor(pr, 32);
    const float s_new = pr;

    float M = s_new;
#pragma unroll
    for (int j = 0; j < 16; ++j)
        M = fmaxf(M, ml2[((b * 16 + j) * 16 + h) * 2]);

    float L = exp2f(s_new - M);
    float O = L * v_ws[vecoff];
#pragma unroll
    for (int j = 0; j < 16; ++j) {
        const int oi = (b * 16 + j) * 16 + h;
        const float mg = ml2[oi * 2 + 0];
        const float lg = ml2[oi * 2 + 1];
        const float sc = exp2f(mg - M);
        L += lg * sc;
        O += o2[(size_t)oi * 64 + d] * sc;
    }
    attn_out[vecoff] = O / L;
}

extern "C" void kernel_launch(void* const* d_in, const int* in_sizes, int n_in,
                              void* d_out, int out_size, void* d_ws, size_t ws_size,
                              hipStream_t stream) {
    const float* hidden      = (const float*)d_in[0];
    const float* key_cache   = (const float*)d_in[1];
    const float* value_cache = (const float*)d_in[2];
    const int*   block_table = (const int*)d_in[3];
    const int*   positions   = (const int*)d_in[4];
    const float* Wq          = (const float*)d_in[5];
    const float* Wk          = (const float*)d_in[6];
    const float* Wv          = (const float*)d_in[7];
    const float* Wo          = (const float*)d_in[8];
    float* out = (float*)d_out;

    float* ws = (float*)d_ws;
    float* q_ws  = ws + Q_OFF;
    float* k_ws  = ws + K_OFF;
    float* v_ws  = ws + V_OFF;
    float* ao_ws = ws + AO_OFF;
    float* part  = ws + PART_OFF;
    int*   items = (int*)(ws + ITEMS_OFF);
    int*   cum   = (int*)(ws + CUM_OFF);
    unsigned* counter = (unsigned*)(ws + CNT_OFF);
    float* pml   = ws + PML_OFF;
    float* po    = ws + PO_OFF;
    float* ml2   = ws + ML2_OFF;
    float* o2    = ws + O2_OFF;

    // 1) q/k/v projections: 3072 rows x 4 column-chunks
    proj_partial<<<dim3(192, CHUNKS), 256, 0, stream>>>(hidden, Wq, Wk, Wv, part, 3072);
    qkv_combine<<<192, 256, 0, stream>>>(part, positions, q_ws, k_ws, v_ws,
                                         items, cum, counter);

    // 2) flash-decode: whole-cache-block items, all heads per wave
    attn_partial<<<NBLOCKS_ATTN, 256, 0, stream>>>(
        q_ws, key_cache, value_cache, block_table, positions,
        items, cum, counter, pml, po);

    // 3) two-level merge + new-token contribution
    attn_reduce1<<<dim3(BATCH, 16), 256, 0, stream>>>(positions, cum, pml, po, ml2, o2);
    attn_reduce2<<<BATCH * NUM_HEADS, 64, 0, stream>>>(q_ws, k_ws, v_ws, ml2, o2, ao_ws);

    // 4) output projection: 1024 rows x 4 column-chunks
    proj_partial<<<dim3(64, CHUNKS), 256, 0, stream>>>(ao_ws, Wo, Wo, Wo, part, 1024);
    out_combine<<<64, 256, 0, stream>>>(part, out);
}

// Round 9
// 97.781 us; speedup vs baseline: 1.6909x; 1.0804x over previous
//
#include <hip/hip_runtime.h>
#include <math.h>

#define BATCH 16
#define NUM_HEADS 16
#define HEAD_DIM 64
#define HIDDEN 1024
#define BLOCK_SIZE 16
#define MAX_CTX 4096
#define BLOCKS_PER_SEQ 256
#define SPLITS 8
#define CHUNKS 4
#define CHUNK_F4 64    // (HIDDEN/CHUNKS)/4

// workspace layout in floats
#define PART_OFF 0            // 3072*16*CHUNKS = 196608 (qkv proj partials)
#define PML_OFF  196608       // BATCH*NUM_HEADS*SPLITS*2 = 4096
#define PO_OFF   200704       // BATCH*NUM_HEADS*SPLITS*64 = 131072
#define AO_OFF   331776       // 16384
// total 348160 floats = 1.4 MB

#define LOG2E 1.4426950408889634f

// Split-K GEMV partial: rows 0..1023 -> Wq, 1024..2047 -> Wk, 2048..3071 -> Wv.
// part layout: part[(row*16 + b)*CHUNKS + c] -- consumers reconstruct one
// (row,b) element with a single float4 load + horizontal sum.
__global__ void proj_partial(const float* __restrict__ X,
                             const float* __restrict__ W0,
                             const float* __restrict__ W1,
                             const float* __restrict__ W2,
                             float* __restrict__ part) {
    const int tid = threadIdx.x;
    const int b = tid & 15;
    const int r = tid >> 4;                  // 0..15
    const int row = blockIdx.x * 16 + r;
    const int c = blockIdx.y;
    const int m = row >> 10;
    const int row_in = row & 1023;
    const float* W = (m == 0) ? W0 : (m == 1) ? W1 : W2;

    const float4* wrow = (const float4*)(W + (size_t)row_in * HIDDEN) + c * CHUNK_F4;
    const float4* xrow = (const float4*)(X + (size_t)b * HIDDEN) + c * CHUNK_F4;
    float acc = 0.f;
#pragma unroll 16
    for (int i = 0; i < CHUNK_F4; ++i) {
        float4 w4 = wrow[i];
        float4 x4 = xrow[i];
        acc += w4.x * x4.x + w4.y * x4.y + w4.z * x4.z + w4.w * x4.w;
    }
    part[((size_t)row * 16 + b) * CHUNKS + c] = acc;
}

// issue 8 x 16B loads for 64-token iteration IT (this wave's 16-token page)
#define LOAD_KV(IT, K0, K1, K2, K3, V0, V1, V2, V3)                              \
    do {                                                                          \
        const int blk_ = bt_lds[(IT) * 4 + w];                                    \
        const size_t base_ = ((size_t)blk_ * BLOCK_SIZE + g) * 1024 + hoff;       \
        const float* kp_ = key_cache + base_;                                     \
        const float* vp_ = value_cache + base_;                                   \
        K0 = *(const float4*)(kp_);                                               \
        K1 = *(const float4*)(kp_ + 4096);                                        \
        K2 = *(const float4*)(kp_ + 8192);                                        \
        K3 = *(const float4*)(kp_ + 12288);                                       \
        V0 = *(const float4*)(vp_);                                               \
        V1 = *(const float4*)(vp_ + 4096);                                        \
        V2 = *(const float4*)(vp_ + 8192);                                        \
        V3 = *(const float4*)(vp_ + 12288);                                       \
    } while (0)

#define COMPUTE(IT, K0, K1, K2, K3, V0, V1, V2, V3)                               \
    do {                                                                          \
        float d0_ = K0.x * q4.x + K0.y * q4.y + K0.z * q4.z + K0.w * q4.w;        \
        float d1_ = K1.x * q4.x + K1.y * q4.y + K1.z * q4.z + K1.w * q4.w;        \
        float d2_ = K2.x * q4.x + K2.y * q4.y + K2.z * q4.z + K2.w * q4.w;        \
        float d3_ = K3.x * q4.x + K3.y * q4.y + K3.z * q4.z + K3.w * q4.w;        \
        d0_ += __shfl_xor(d0_, 1); d1_ += __shfl_xor(d1_, 1);                     \
        d2_ += __shfl_xor(d2_, 1); d3_ += __shfl_xor(d3_, 1);                     \
        d0_ += __shfl_xor(d0_, 2); d1_ += __shfl_xor(d1_, 2);                     \
        d2_ += __shfl_xor(d2_, 2); d3_ += __shfl_xor(d3_, 2);                     \
        d0_ += __shfl_xor(d0_, 4); d1_ += __shfl_xor(d1_, 4);                     \
        d2_ += __shfl_xor(d2_, 4); d3_ += __shfl_xor(d3_, 4);                     \
        d0_ += __shfl_xor(d0_, 8); d1_ += __shfl_xor(d1_, 8);                     \
        d2_ += __shfl_xor(d2_, 8); d3_ += __shfl_xor(d3_, 8);                     \
        const int tb_ = t0 + (IT) * 64 + w * 16 + g;                              \
        if (tb_ + 0  >= t1) d0_ = -INFINITY;                                      \
        if (tb_ + 4  >= t1) d1_ = -INFINITY;                                      \
        if (tb_ + 8  >= t1) d2_ = -INFINITY;                                      \
        if (tb_ + 12 >= t1) d3_ = -INFINITY;                                      \
        const float mx_ = fmaxf(fmaxf(d0_, d1_), fmaxf(d2_, d3_));                \
        const float m_new_ = fmaxf(m, mx_);                                       \
        const float corr_ = exp2f(m - m_new_);                                    \
        const float p0_ = exp2f(d0_ - m_new_);                                    \
        const float p1_ = exp2f(d1_ - m_new_);                                    \
        const float p2_ = exp2f(d2_ - m_new_);                                    \
        const float p3_ = exp2f(d3_ - m_new_);                                    \
        l = l * corr_ + ((p0_ + p1_) + (p2_ + p3_));                              \
        o4.x = o4.x * corr_ + p0_ * V0.x + p1_ * V1.x + p2_ * V2.x + p3_ * V3.x;  \
        o4.y = o4.y * corr_ + p0_ * V0.y + p1_ * V1.y + p2_ * V2.y + p3_ * V3.y;  \
        o4.z = o4.z * corr_ + p0_ * V0.z + p1_ * V1.z + p2_ * V2.z + p3_ * V3.z;  \
        o4.w = o4.w * corr_ + p0_ * V0.w + p1_ * V1.w + p2_ * V2.w + p3_ * V3.w;  \
        m = m_new_;                                                               \
    } while (0)

// Flash-decode partial: grid (SPLITS, NUM_HEADS, BATCH), 256 threads.
// Balanced splits (chunk = ceil(pos/(SPLITS*64))*64), ping-pong K/V loads,
// q combined in-prologue from the transposed projection partials.
__global__ void attn_partial(const float* __restrict__ part,
                             const float* __restrict__ key_cache,
                             const float* __restrict__ value_cache,
                             const int* __restrict__ block_table,
                             const int* __restrict__ positions,
                             float* __restrict__ part_ml,
                             float* __restrict__ part_o) {
    const int s = blockIdx.x;
    const int h = blockIdx.y;
    const int b = blockIdx.z;
    const int tid = threadIdx.x;          // 0..255
    const int lane = tid & 63;
    const int w = tid >> 6;               // wave 0..3
    const int g = lane >> 4;              // group-in-wave 0..3
    const int sub = lane & 15;            // 0..15
    const int gid = w * 4 + g;            // 0..15

    __shared__ int bt_lds[32];
    __shared__ float gm[16];
    __shared__ float gl[16];
    __shared__ float go[16][64];

    const int pos = positions[b];
    const int chunk = ((pos + SPLITS * 64 - 1) / (SPLITS * 64)) * 64;  // mult of 64
    const int t0 = s * chunk;
    const int t1 = min(t0 + chunk, pos);
    const int nvalid = t1 - t0;
    const int niter = (nvalid + 63) >> 6;

    // combine q[b][h][sub*4..sub*4+3] from 4-chunk partials (R4-verified)
    const int hbase = h * HEAD_DIM + sub * 4;   // q rows are 0..1023
    const float4 pq0 = ((const float4*)part)[(hbase + 0) * 16 + b];
    const float4 pq1 = ((const float4*)part)[(hbase + 1) * 16 + b];
    const float4 pq2 = ((const float4*)part)[(hbase + 2) * 16 + b];
    const float4 pq3 = ((const float4*)part)[(hbase + 3) * 16 + b];

    // stage 32 entries; t0>>4 <= 224 so index <= 255: always in-bounds.
    if (tid < 32) {
        bt_lds[tid] = block_table[b * BLOCKS_PER_SEQ + (t0 >> 4) + tid];
    }
    __syncthreads();

    const float qs = 0.125f * LOG2E;   // 1/sqrt(64) * log2(e)
    float4 q4;
    q4.x = (pq0.x + pq0.y + pq0.z + pq0.w) * qs;
    q4.y = (pq1.x + pq1.y + pq1.z + pq1.w) * qs;
    q4.z = (pq2.x + pq2.y + pq2.z + pq2.w) * qs;
    q4.w = (pq3.x + pq3.y + pq3.z + pq3.w) * qs;
    const int hoff = h * HEAD_DIM + sub * 4;

    float m = -1e30f;
    float l = 0.f;
    float4 o4 = {0.f, 0.f, 0.f, 0.f};

    float4 kA0, kA1, kA2, kA3, vA0, vA1, vA2, vA3;
    float4 kB0, kB1, kB2, kB3, vB0, vB1, vB2, vB3;

    if (niter > 0) {
        LOAD_KV(0, kA0, kA1, kA2, kA3, vA0, vA1, vA2, vA3);
        int it = 0;
        while (true) {
            if (it + 1 < niter) LOAD_KV(it + 1, kB0, kB1, kB2, kB3, vB0, vB1, vB2, vB3);
            COMPUTE(it, kA0, kA1, kA2, kA3, vA0, vA1, vA2, vA3);
            ++it;
            if (it >= niter) break;
            if (it + 1 < niter) LOAD_KV(it + 1, kA0, kA1, kA2, kA3, vA0, vA1, vA2, vA3);
            COMPUTE(it, kB0, kB1, kB2, kB3, vB0, vB1, vB2, vB3);
            ++it;
            if (it >= niter) break;
        }
    }

    go[gid][sub * 4 + 0] = o4.x;
    go[gid][sub * 4 + 1] = o4.y;
    go[gid][sub * 4 + 2] = o4.z;
    go[gid][sub * 4 + 3] = o4.w;
    if (sub == 0) { gm[gid] = m; gl[gid] = l; }
    __syncthreads();

    if (tid < 64) {
        const int d = tid;
        float M = -1e30f;
#pragma unroll
        for (int gi = 0; gi < 16; ++gi) M = fmaxf(M, gm[gi]);
        float L = 0.f, O = 0.f;
#pragma unroll
        for (int gi = 0; gi < 16; ++gi) {
            const float sc = exp2f(gm[gi] - M);   // log2-domain maxes
            L += gl[gi] * sc;
            O += go[gi][d] * sc;
        }
        const int pidx = (b * NUM_HEADS + h) * SPLITS + s;
        part_o[(size_t)pidx * 64 + d] = O;
        if (d == 0) {
            part_ml[pidx * 2 + 0] = M;   // log2 domain
            part_ml[pidx * 2 + 1] = L;
        }
    }
}

// Merge split partials + the new-token (tok == pos) term, q/k/v combined
// from the transposed projection partials (R4-verified). grid = B*H, 64 thr.
__global__ void attn_reduce(const float* __restrict__ part,
                            const float* __restrict__ part_ml,
                            const float* __restrict__ part_o,
                            float* __restrict__ attn_out) {
    const int bh = blockIdx.x;          // b*16 + h
    const int b = bh >> 4;
    const int h = bh & 15;
    const int d = threadIdx.x;          // 0..63

    const int row = h * HEAD_DIM + d;
    const float4 pq = ((const float4*)part)[(0    + row) * 16 + b];
    const float4 pk = ((const float4*)part)[(1024 + row) * 16 + b];
    const float4 pv = ((const float4*)part)[(2048 + row) * 16 + b];
    const float qd = pq.x + pq.y + pq.z + pq.w;
    const float kd = pk.x + pk.y + pk.z + pk.w;
    const float vd = pv.x + pv.y + pv.z + pv.w;

    float pr = qd * kd;
    pr += __shfl_xor(pr, 1);
    pr += __shfl_xor(pr, 2);
    pr += __shfl_xor(pr, 4);
    pr += __shfl_xor(pr, 8);
    pr += __shfl_xor(pr, 16);
    pr += __shfl_xor(pr, 32);
    const float s_new = pr * (0.125f * LOG2E);   // log2 domain

    float2 ml0 = ((const float2*)part_ml)[bh * SPLITS + 0];
    float2 ml1 = ((const float2*)part_ml)[bh * SPLITS + 1];
    float2 ml2 = ((const float2*)part_ml)[bh * SPLITS + 2];
    float2 ml3 = ((const float2*)part_ml)[bh * SPLITS + 3];
    float2 ml4 = ((const float2*)part_ml)[bh * SPLITS + 4];
    float2 ml5 = ((const float2*)part_ml)[bh * SPLITS + 5];
    float2 ml6 = ((const float2*)part_ml)[bh * SPLITS + 6];
    float2 ml7 = ((const float2*)part_ml)[bh * SPLITS + 7];

    float M = s_new;
    M = fmaxf(M, fmaxf(fmaxf(ml0.x, ml1.x), fmaxf(ml2.x, ml3.x)));
    M = fmaxf(M, fmaxf(fmaxf(ml4.x, ml5.x), fmaxf(ml6.x, ml7.x)));

    const float sc0 = exp2f(ml0.x - M), sc1 = exp2f(ml1.x - M);
    const float sc2 = exp2f(ml2.x - M), sc3 = exp2f(ml3.x - M);
    const float sc4 = exp2f(ml4.x - M), sc5 = exp2f(ml5.x - M);
    const float sc6 = exp2f(ml6.x - M), sc7 = exp2f(ml7.x - M);

    const float e_new = exp2f(s_new - M);
    float L = e_new
            + ml0.y * sc0 + ml1.y * sc1 + ml2.y * sc2 + ml3.y * sc3
            + ml4.y * sc4 + ml5.y * sc5 + ml6.y * sc6 + ml7.y * sc7;
    float O = e_new * vd;
    const float* po = part_o + (size_t)bh * SPLITS * 64 + d;
    O += po[0 * 64] * sc0 + po[1 * 64] * sc1 + po[2 * 64] * sc2 + po[3 * 64] * sc3
       + po[4 * 64] * sc4 + po[5 * 64] * sc5 + po[6 * 64] * sc6 + po[7 * 64] * sc7;

    attn_out[(size_t)b * HIDDEN + h * HEAD_DIM + d] = O / L;
}

// Output projection, fused split-K-by-16 inside the block, writes d_out.
// grid (64 rowgroups, 16 batches) x 256 thr; thread (r = tid>>4, c = tid&15)
// covers out row rg*16+r, K-chunk c (64 floats); shfl-reduce over c.
__global__ void wo_proj(const float* __restrict__ ao,
                        const float* __restrict__ Wo,
                        float* __restrict__ out) {
    const int rg = blockIdx.x;
    const int b = blockIdx.y;
    const int r = threadIdx.x >> 4;
    const int c = threadIdx.x & 15;
    const int row = rg * 16 + r;

    const float4* wrow = (const float4*)(Wo + (size_t)row * HIDDEN) + c * 16;
    const float4* arow = (const float4*)(ao + (size_t)b * HIDDEN) + c * 16;
    float acc = 0.f;
#pragma unroll
    for (int i = 0; i < 16; ++i) {
        float4 w4 = wrow[i];
        float4 a4 = arow[i];
        acc += w4.x * a4.x + w4.y * a4.y + w4.z * a4.z + w4.w * a4.w;
    }
    acc += __shfl_xor(acc, 1);
    acc += __shfl_xor(acc, 2);
    acc += __shfl_xor(acc, 4);
    acc += __shfl_xor(acc, 8);
    if (c == 0) out[(size_t)b * HIDDEN + row] = acc;
}

extern "C" void kernel_launch(void* const* d_in, const int* in_sizes, int n_in,
                              void* d_out, int out_size, void* d_ws, size_t ws_size,
                              hipStream_t stream) {
    const float* hidden      = (const float*)d_in[0];
    const float* key_cache   = (const float*)d_in[1];
    const float* value_cache = (const float*)d_in[2];
    const int*   block_table = (const int*)d_in[3];
    const int*   positions   = (const int*)d_in[4];
    const float* Wq          = (const float*)d_in[5];
    const float* Wk          = (const float*)d_in[6];
    const float* Wv          = (const float*)d_in[7];
    const float* Wo          = (const float*)d_in[8];
    float* out = (float*)d_out;

    float* ws = (float*)d_ws;
    float* part  = ws + PART_OFF;
    float* pml   = ws + PML_OFF;
    float* po    = ws + PO_OFF;
    float* ao_ws = ws + AO_OFF;

    // 1) q/k/v projection partials: 3072 rows x 4 column-chunks (transposed)
    proj_partial<<<dim3(192, CHUNKS), 256, 0, stream>>>(hidden, Wq, Wk, Wv, part);

    // 2) flash-decode partials (q combined in-prologue)
    attn_partial<<<dim3(SPLITS, NUM_HEADS, BATCH), 256, 0, stream>>>(
        part, key_cache, value_cache, block_table, positions, pml, po);

    // 3) merge splits + new-token contribution (q/k/v from part)
    attn_reduce<<<BATCH * NUM_HEADS, 64, 0, stream>>>(part, pml, po, ao_ws);

    // 4) output projection straight to d_out
    wo_proj<<<dim3(64, BATCH), 256, 0, stream>>>(ao_ws, Wo, out);
}

// Round 11
// 94.101 us; speedup vs baseline: 1.7571x; 1.0391x over previous
//
#include <hip/hip_runtime.h>
#include <math.h>

#define BATCH 16
#define NUM_HEADS 16
#define HEAD_DIM 64
#define HIDDEN 1024
#define BLOCK_SIZE 16
#define MAX_CTX 4096
#define BLOCKS_PER_SEQ 256
#define SPLITS 8
#define CHUNKS 4
#define CHUNK_F4 64    // (HIDDEN/CHUNKS)/4

// workspace layout in floats (R3/R6 layout)
#define Q_OFF   0                  // 16384 floats (q pre-scaled by 0.125*log2e)
#define K_OFF   16384
#define V_OFF   32768
#define AO_OFF  49152
#define PML_OFF 65536              // BATCH*NUM_HEADS*SPLITS*2 = 4096
#define PO_OFF  69632              // BATCH*NUM_HEADS*SPLITS*64 = 131072
#define PART_OFF 200704            // CHUNKS*3072*16 = 196608

#define LOG2E 1.4426950408889634f

// Native vector type accepted by __builtin_nontemporal_load (HIP_vector_type
// float4 is a class and is rejected). Same 16B layout.
typedef float nfloat4 __attribute__((ext_vector_type(4)));

// Non-temporal (no L3 allocate) 16B load: K/V and weight streams are
// single-visit; nt avoids evicting the harness-fill-dirtied L3 lines
// (each eviction = writeback to HBM, halving apparent read BW).
__device__ __forceinline__ float4 ldnt4(const float* p) {
    nfloat4 v = __builtin_nontemporal_load(reinterpret_cast<const nfloat4*>(p));
    return make_float4(v.x, v.y, v.z, v.w);
}

// Split-K GEMV partial: rows 0..1023 -> W0, 1024..2047 -> W1, 2048..3071 -> W2.
// part layout: part[(c*NR + row)*16 + b]
__global__ void proj_partial(const float* __restrict__ X,
                             const float* __restrict__ W0,
                             const float* __restrict__ W1,
                             const float* __restrict__ W2,
                             float* __restrict__ part, int NR) {
    const int tid = threadIdx.x;
    const int b = tid & 15;
    const int r = tid >> 4;                  // 0..15
    const int row = blockIdx.x * 16 + r;
    const int c = blockIdx.y;
    const int m = row >> 10;
    const int row_in = row & 1023;
    const float* W = (m == 0) ? W0 : (m == 1) ? W1 : W2;

    const float* wrow = W + (size_t)row_in * HIDDEN + c * (CHUNK_F4 * 4);
    const float4* xrow = (const float4*)(X + (size_t)b * HIDDEN) + c * CHUNK_F4;
    float acc = 0.f;
#pragma unroll 16
    for (int i = 0; i < CHUNK_F4; ++i) {
        float4 w4 = ldnt4(wrow + i * 4);   // weights: single-visit stream
        float4 x4 = xrow[i];
        acc += w4.x * x4.x + w4.y * x4.y + w4.z * x4.z + w4.w * x4.w;
    }
    part[((size_t)c * NR + row) * 16 + b] = acc;
}

// Combine q/k/v partials; q gets pre-scaled by 0.125*log2e.
__global__ void qkv_combine(const float* __restrict__ part,
                            float* __restrict__ q_ws,
                            float* __restrict__ k_ws,
                            float* __restrict__ v_ws) {
    const int idx = blockIdx.x * 256 + threadIdx.x;  // row*16 + b, rows 0..3071
    const int row = idx >> 4;
    const int b = idx & 15;
    float s = 0.f;
#pragma unroll
    for (int c = 0; c < CHUNKS; ++c) s += part[((size_t)c * 3072 + row) * 16 + b];
    const int m = row >> 10;
    const int r = row & 1023;
    if (m == 0)      q_ws[b * HIDDEN + r] = s * (0.125f * LOG2E);
    else if (m == 1) k_ws[b * HIDDEN + r] = s;
    else             v_ws[b * HIDDEN + r] = s;
}

// Final combine for the output projection (rows 0..1023).
__global__ void out_combine(const float* __restrict__ part,
                            float* __restrict__ out) {
    const int idx = blockIdx.x * 256 + threadIdx.x;  // row*16 + b
    const int row = idx >> 4;
    const int b = idx & 15;
    float s = 0.f;
#pragma unroll
    for (int c = 0; c < CHUNKS; ++c) s += part[((size_t)c * 1024 + row) * 16 + b];
    out[(size_t)b * HIDDEN + row] = s;
}

// issue 8 x 16B non-temporal loads for 64-token iteration IT
#define LOAD_KV(IT, K0, K1, K2, K3, V0, V1, V2, V3)                              \
    do {                                                                          \
        const int blk_ = bt_lds[(IT) * 4 + w];                                    \
        const size_t base_ = ((size_t)blk_ * BLOCK_SIZE + g) * 1024 + hoff;       \
        const float* kp_ = key_cache + base_;                                     \
        const float* vp_ = value_cache + base_;                                   \
        K0 = ldnt4(kp_);                                                          \
        K1 = ldnt4(kp_ + 4096);                                                   \
        K2 = ldnt4(kp_ + 8192);                                                   \
        K3 = ldnt4(kp_ + 12288);                                                  \
        V0 = ldnt4(vp_);                                                          \
        V1 = ldnt4(vp_ + 4096);                                                   \
        V2 = ldnt4(vp_ + 8192);                                                   \
        V3 = ldnt4(vp_ + 12288);                                                  \
    } while (0)

#define COMPUTE(IT, K0, K1, K2, K3, V0, V1, V2, V3)                               \
    do {                                                                          \
        float d0_ = K0.x * q4.x + K0.y * q4.y + K0.z * q4.z + K0.w * q4.w;        \
        float d1_ = K1.x * q4.x + K1.y * q4.y + K1.z * q4.z + K1.w * q4.w;        \
        float d2_ = K2.x * q4.x + K2.y * q4.y + K2.z * q4.z + K2.w * q4.w;        \
        float d3_ = K3.x * q4.x + K3.y * q4.y + K3.z * q4.z + K3.w * q4.w;        \
        d0_ += __shfl_xor(d0_, 1); d1_ += __shfl_xor(d1_, 1);                     \
        d2_ += __shfl_xor(d2_, 1); d3_ += __shfl_xor(d3_, 1);                     \
        d0_ += __shfl_xor(d0_, 2); d1_ += __shfl_xor(d1_, 2);                     \
        d2_ += __shfl_xor(d2_, 2); d3_ += __shfl_xor(d3_, 2);                     \
        d0_ += __shfl_xor(d0_, 4); d1_ += __shfl_xor(d1_, 4);                     \
        d2_ += __shfl_xor(d2_, 4); d3_ += __shfl_xor(d3_, 4);                     \
        d0_ += __shfl_xor(d0_, 8); d1_ += __shfl_xor(d1_, 8);                     \
        d2_ += __shfl_xor(d2_, 8); d3_ += __shfl_xor(d3_, 8);                     \
        const int tb_ = t0 + (IT) * 64 + w * 16 + g;                              \
        if (tb_ + 0  >= t1) d0_ = -INFINITY;                                      \
        if (tb_ + 4  >= t1) d1_ = -INFINITY;                                      \
        if (tb_ + 8  >= t1) d2_ = -INFINITY;                                      \
        if (tb_ + 12 >= t1) d3_ = -INFINITY;                                      \
        const float mx_ = fmaxf(fmaxf(d0_, d1_), fmaxf(d2_, d3_));                \
        const float m_new_ = fmaxf(m, mx_);                                       \
        const float corr_ = exp2f(m - m_new_);                                    \
        const float p0_ = exp2f(d0_ - m_new_);                                    \
        const float p1_ = exp2f(d1_ - m_new_);                                    \
        const float p2_ = exp2f(d2_ - m_new_);                                    \
        const float p3_ = exp2f(d3_ - m_new_);                                    \
        l = l * corr_ + ((p0_ + p1_) + (p2_ + p3_));                              \
        o4.x = o4.x * corr_ + p0_ * V0.x + p1_ * V1.x + p2_ * V2.x + p3_ * V3.x;  \
        o4.y = o4.y * corr_ + p0_ * V0.y + p1_ * V1.y + p2_ * V2.y + p3_ * V3.y;  \
        o4.z = o4.z * corr_ + p0_ * V0.z + p1_ * V1.z + p2_ * V2.z + p3_ * V3.z;  \
        o4.w = o4.w * corr_ + p0_ * V0.w + p1_ * V1.w + p2_ * V2.w + p3_ * V3.w;  \
        m = m_new_;                                                               \
    } while (0)

// Flash-decode partial: grid (SPLITS, NUM_HEADS, BATCH), 256 threads.
// Balanced splits: split s covers [s*chunk, min((s+1)*chunk, pos)),
// chunk = ceil(pos/(SPLITS*64))*64. Ping-pong double-buffered nt K/V loads.
__global__ __launch_bounds__(256, 4) void attn_partial(
                             const float* __restrict__ q_ws,
                             const float* __restrict__ key_cache,
                             const float* __restrict__ value_cache,
                             const int* __restrict__ block_table,
                             const int* __restrict__ positions,
                             float* __restrict__ part_ml,
                             float* __restrict__ part_o) {
    const int s = blockIdx.x;
    const int h = blockIdx.y;
    const int b = blockIdx.z;
    const int tid = threadIdx.x;          // 0..255
    const int lane = tid & 63;
    const int w = tid >> 6;               // wave 0..3
    const int g = lane >> 4;              // group-in-wave 0..3
    const int sub = lane & 15;            // 0..15
    const int gid = w * 4 + g;            // 0..15

    __shared__ int bt_lds[32];
    __shared__ float gm[16];
    __shared__ float gl[16];
    __shared__ float go[16][64];

    const int pos = positions[b];
    const int chunk = ((pos + SPLITS * 64 - 1) / (SPLITS * 64)) * 64;  // mult of 64
    const int t0 = s * chunk;
    const int t1 = min(t0 + chunk, pos);
    const int nvalid = t1 - t0;
    const int niter = (nvalid + 63) >> 6;

    // q load (pre-scaled) is independent of LDS -- issue before the barrier
    float4 q4 = ((const float4*)(q_ws + (size_t)b * HIDDEN + h * HEAD_DIM))[sub];

    // stage 32 entries; t0>>4 <= 224 so index <= 255: always in-bounds.
    if (tid < 32) {
        bt_lds[tid] = block_table[b * BLOCKS_PER_SEQ + (t0 >> 4) + tid];
    }
    __syncthreads();

    const int hoff = h * HEAD_DIM + sub * 4;

    float m = -1e30f;
    float l = 0.f;
    float4 o4 = {0.f, 0.f, 0.f, 0.f};

    float4 kA0, kA1, kA2, kA3, vA0, vA1, vA2, vA3;
    float4 kB0, kB1, kB2, kB3, vB0, vB1, vB2, vB3;

    if (niter > 0) {
        LOAD_KV(0, kA0, kA1, kA2, kA3, vA0, vA1, vA2, vA3);
        int it = 0;
        while (true) {
            if (it + 1 < niter) LOAD_KV(it + 1, kB0, kB1, kB2, kB3, vB0, vB1, vB2, vB3);
            COMPUTE(it, kA0, kA1, kA2, kA3, vA0, vA1, vA2, vA3);
            ++it;
            if (it >= niter) break;
            if (it + 1 < niter) LOAD_KV(it + 1, kA0, kA1, kA2, kA3, vA0, vA1, vA2, vA3);
            COMPUTE(it, kB0, kB1, kB2, kB3, vB0, vB1, vB2, vB3);
            ++it;
            if (it >= niter) break;
        }
    }

    go[gid][sub * 4 + 0] = o4.x;
    go[gid][sub * 4 + 1] = o4.y;
    go[gid][sub * 4 + 2] = o4.z;
    go[gid][sub * 4 + 3] = o4.w;
    if (sub == 0) { gm[gid] = m; gl[gid] = l; }
    __syncthreads();

    if (tid < 64) {
        const int d = tid;
        float M = -1e30f;
#pragma unroll
        for (int gi = 0; gi < 16; ++gi) M = fmaxf(M, gm[gi]);
        float L = 0.f, O = 0.f;
#pragma unroll
        for (int gi = 0; gi < 16; ++gi) {
            const float sc = exp2f(gm[gi] - M);   // log2-domain maxes
            L += gl[gi] * sc;
            O += go[gi][d] * sc;
        }
        const int pidx = (b * NUM_HEADS + h) * SPLITS + s;
        part_o[(size_t)pidx * 64 + d] = O;
        if (d == 0) {
            part_ml[pidx * 2 + 0] = M;   // log2 domain
            part_ml[pidx * 2 + 1] = L;
        }
    }
}

// Merge split partials + the new-token (tok == pos) term. grid = B*H, 64 thr.
__global__ void attn_reduce(const float* __restrict__ q_ws,
                            const float* __restrict__ k_ws,
                            const float* __restrict__ v_ws,
                            const float* __restrict__ part_ml,
                            const float* __restrict__ part_o,
                            float* __restrict__ attn_out) {
    const int bh = blockIdx.x;          // b*16 + h
    const int b = bh >> 4;
    const int h = bh & 15;
    const int d = threadIdx.x;          // 0..63

    const size_t vecoff = (size_t)b * HIDDEN + h * HEAD_DIM + d;
    const float qd = q_ws[vecoff];      // pre-scaled -> dot is log2-domain
    const float kd = k_ws[vecoff];
    float pr = qd * kd;
    pr += __shfl_xor(pr, 1);
    pr += __shfl_xor(pr, 2);
    pr += __shfl_xor(pr, 4);
    pr += __shfl_xor(pr, 8);
    pr += __shfl_xor(pr, 16);
    pr += __shfl_xor(pr, 32);
    const float s_new = pr;

    float2 ml0 = ((const float2*)part_ml)[bh * SPLITS + 0];
    float2 ml1 = ((const float2*)part_ml)[bh * SPLITS + 1];
    float2 ml2 = ((const float2*)part_ml)[bh * SPLITS + 2];
    float2 ml3 = ((const float2*)part_ml)[bh * SPLITS + 3];
    float2 ml4 = ((const float2*)part_ml)[bh * SPLITS + 4];
    float2 ml5 = ((const float2*)part_ml)[bh * SPLITS + 5];
    float2 ml6 = ((const float2*)part_ml)[bh * SPLITS + 6];
    float2 ml7 = ((const float2*)part_ml)[bh * SPLITS + 7];

    float M = s_new;
    M = fmaxf(M, fmaxf(fmaxf(ml0.x, ml1.x), fmaxf(ml2.x, ml3.x)));
    M = fmaxf(M, fmaxf(fmaxf(ml4.x, ml5.x), fmaxf(ml6.x, ml7.x)));

    const float sc0 = exp2f(ml0.x - M), sc1 = exp2f(ml1.x - M);
    const float sc2 = exp2f(ml2.x - M), sc3 = exp2f(ml3.x - M);
    const float sc4 = exp2f(ml4.x - M), sc5 = exp2f(ml5.x - M);
    const float sc6 = exp2f(ml6.x - M), sc7 = exp2f(ml7.x - M);

    const float e_new = exp2f(s_new - M);
    float L = e_new
            + ml0.y * sc0 + ml1.y * sc1 + ml2.y * sc2 + ml3.y * sc3
            + ml4.y * sc4 + ml5.y * sc5 + ml6.y * sc6 + ml7.y * sc7;
    float O = e_new * v_ws[vecoff];
    const float* po = part_o + (size_t)bh * SPLITS * 64 + d;
    O += po[0 * 64] * sc0 + po[1 * 64] * sc1 + po[2 * 64] * sc2 + po[3 * 64] * sc3
       + po[4 * 64] * sc4 + po[5 * 64] * sc5 + po[6 * 64] * sc6 + po[7 * 64] * sc7;

    attn_out[vecoff] = O / L;
}

extern "C" void kernel_launch(void* const* d_in, const int* in_sizes, int n_in,
                              void* d_out, int out_size, void* d_ws, size_t ws_size,
                              hipStream_t stream) {
    const float* hidden      = (const float*)d_in[0];
    const float* key_cache   = (const float*)d_in[1];
    const float* value_cache = (const float*)d_in[2];
    const int*   block_table = (const int*)d_in[3];
    const int*   positions   = (const int*)d_in[4];
    const float* Wq          = (const float*)d_in[5];
    const float* Wk          = (const float*)d_in[6];
    const float* Wv          = (const float*)d_in[7];
    const float* Wo          = (const float*)d_in[8];
    float* out = (float*)d_out;

    float* ws = (float*)d_ws;
    float* q_ws  = ws + Q_OFF;
    float* k_ws  = ws + K_OFF;
    float* v_ws  = ws + V_OFF;
    float* ao_ws = ws + AO_OFF;
    float* pml   = ws + PML_OFF;
    float* po    = ws + PO_OFF;
    float* part  = ws + PART_OFF;

    // 1) q/k/v projections: 3072 rows x 4 column-chunks
    proj_partial<<<dim3(192, CHUNKS), 256, 0, stream>>>(hidden, Wq, Wk, Wv, part, 3072);
    qkv_combine<<<192, 256, 0, stream>>>(part, q_ws, k_ws, v_ws);

    // 2) flash-decode partials over the (unmodified) caches
    attn_partial<<<dim3(SPLITS, NUM_HEADS, BATCH), 256, 0, stream>>>(
        q_ws, key_cache, value_cache, block_table, positions, pml, po);

    // 3) merge splits + new-token contribution
    attn_reduce<<<BATCH * NUM_HEADS, 64, 0, stream>>>(q_ws, k_ws, v_ws, pml, po, ao_ws);

    // 4) output projection: 1024 rows x 4 column-chunks
    proj_partial<<<dim3(64, CHUNKS), 256, 0, stream>>>(ao_ws, Wo, Wo, Wo, part, 1024);
    out_combine<<<64, 256, 0, stream>>>(part, out);
}